// Round 1
// baseline (342.889 us; speedup 1.0000x reference)
//
#include <hip/hip_runtime.h>

// Problem constants (from reference):
//   lat: [2048,2048] fp32 -> z rows N = 2048*2048/32 = 131072, D = 32
//   centroids: [1024, 32] fp32, K = 1024
//   out: [4194304 scaled lat] ++ [1 loss scalar]
#define D 32
#define K 1024
#define N_ROWS 131072
#define TOTAL_ELEMS 4194304
#define LOSS_SCALE (1.25f / 4194304.0f)   // (1+beta)/ (N*D)

// ---------------- Kernel 1: out = lat * clamp(lf); zero the loss slot ----
__global__ __launch_bounds__(256) void scale_kernel(
    const float* __restrict__ lat, const float* __restrict__ lf_ptr,
    float* __restrict__ out) {
  float lf = lf_ptr[0];
  lf = fminf(fmaxf(lf, 0.001f), 1000.0f);
  int idx = blockIdx.x * blockDim.x + threadIdx.x;
  const float4* in4 = (const float4*)lat;
  float4* out4 = (float4*)out;
  const int n4 = TOTAL_ELEMS / 4;
  for (int i = idx; i < n4; i += gridDim.x * blockDim.x) {
    float4 v = in4[i];
    v.x *= lf; v.y *= lf; v.z *= lf; v.w *= lf;
    out4[i] = v;
  }
  if (idx == 0) out[TOTAL_ELEMS] = 0.0f;  // loss accumulator (stream-ordered before vq)
}

// ---------------- Kernel 2: cnorm[k] = ||c_k||^2 into workspace ----------
__global__ __launch_bounds__(256) void cnorm_kernel(
    const float* __restrict__ cent, float* __restrict__ cnorm) {
  int k = blockIdx.x * blockDim.x + threadIdx.x;
  if (k < K) {
    const float* c = cent + k * D;
    float s0 = 0.f, s1 = 0.f, s2 = 0.f, s3 = 0.f;
#pragma unroll
    for (int d = 0; d < D; d += 4) {
      s0 = fmaf(c[d], c[d], s0);
      s1 = fmaf(c[d + 1], c[d + 1], s1);
      s2 = fmaf(c[d + 2], c[d + 2], s2);
      s3 = fmaf(c[d + 3], c[d + 3], s3);
    }
    cnorm[k] = (s0 + s1) + (s2 + s3);
  }
}

// ---------------- Kernel 3: per-row argmin over K, exact d_min, reduce ---
__global__ __launch_bounds__(256) void vq_kernel(
    const float* __restrict__ lat, const float* __restrict__ cent,
    const float* __restrict__ cnorm, float* __restrict__ loss_out) {
  const int row = blockIdx.x * blockDim.x + threadIdx.x;  // 0..N_ROWS-1

  // Load this thread's 32-dim row into registers (float4 x 8).
  float z[D];
  const float4* z4 = (const float4*)(lat + (size_t)row * D);
#pragma unroll
  for (int i = 0; i < D / 4; ++i) {
    float4 v = z4[i];
    z[4 * i + 0] = v.x; z[4 * i + 1] = v.y;
    z[4 * i + 2] = v.z; z[4 * i + 3] = v.w;
  }

  // Argmin over centroids. k is wave-uniform -> centroid loads scalarize.
  float best = 3.4e38f;
  int bestk = 0;
  for (int k = 0; k < K; ++k) {
    const float* c = cent + k * D;
    float d0 = 0.f, d1 = 0.f, d2 = 0.f, d3 = 0.f;
#pragma unroll
    for (int d = 0; d < D; d += 4) {
      d0 = fmaf(z[d + 0], c[d + 0], d0);
      d1 = fmaf(z[d + 1], c[d + 1], d1);
      d2 = fmaf(z[d + 2], c[d + 2], d2);
      d3 = fmaf(z[d + 3], c[d + 3], d3);
    }
    float dot = (d0 + d1) + (d2 + d3);
    float score = fmaf(-2.f, dot, cnorm[k]);  // ||z||^2 dropped (row-constant)
    if (score < best) { best = score; bestk = k; }
  }

  // Exact fp32 recompute of min distance (immune to argmin near-tie flips).
  const float* cb = cent + bestk * D;
  float m0 = 0.f, m1 = 0.f, m2 = 0.f, m3 = 0.f;
#pragma unroll
  for (int d = 0; d < D; d += 4) {
    float f0 = z[d + 0] - cb[d + 0];
    float f1 = z[d + 1] - cb[d + 1];
    float f2 = z[d + 2] - cb[d + 2];
    float f3 = z[d + 3] - cb[d + 3];
    m0 = fmaf(f0, f0, m0); m1 = fmaf(f1, f1, m1);
    m2 = fmaf(f2, f2, m2); m3 = fmaf(f3, f3, m3);
  }
  float dmin = (m0 + m1) + (m2 + m3);

  // Wave (64-lane) reduction, then cross-wave via LDS, one atomic per block.
#pragma unroll
  for (int off = 32; off > 0; off >>= 1) dmin += __shfl_down(dmin, off);

  __shared__ float wsum[4];  // 256 threads = 4 waves
  const int lane = threadIdx.x & 63;
  const int wave = threadIdx.x >> 6;
  if (lane == 0) wsum[wave] = dmin;
  __syncthreads();
  if (threadIdx.x == 0) {
    float s = (wsum[0] + wsum[1]) + (wsum[2] + wsum[3]);
    atomicAdd(loss_out, s * LOSS_SCALE);
  }
}

extern "C" void kernel_launch(void* const* d_in, const int* in_sizes, int n_in,
                              void* d_out, int out_size, void* d_ws, size_t ws_size,
                              hipStream_t stream) {
  const float* lat  = (const float*)d_in[0];   // 4194304
  const float* cent = (const float*)d_in[1];   // 32768
  const float* lf   = (const float*)d_in[2];   // 1
  float* out = (float*)d_out;                  // 4194304 + 1
  float* cnorm = (float*)d_ws;                 // 1024 floats scratch

  // 1) scaled copy + zero loss slot
  scale_kernel<<<4096, 256, 0, stream>>>(lat, lf, out);
  // 2) centroid norms
  cnorm_kernel<<<(K + 255) / 256, 256, 0, stream>>>(cent, cnorm);
  // 3) VQ argmin + loss
  vq_kernel<<<N_ROWS / 256, 256, 0, stream>>>(lat, cent, cnorm, out + TOTAL_ELEMS);
}

// Round 3
// 118.703 us; speedup vs baseline: 2.8886x; 2.8886x over previous
//
#include <hip/hip_runtime.h>

// Problem: lat [2048,2048] fp32 -> 131072 rows of D=32; centroids [1024,32] fp32.
// out = [lat * clamp(lf, 1e-3, 1e3)] ++ [1.25 * mean_over_NxD(min_k ||z-c_k||^2)]
#define D 32
#define K 1024
#define N_ROWS 131072
#define TOTAL_ELEMS 4194304
#define LOSS_SCALE (1.25f / 4194304.0f)
#define BIAS 192.0f   // makes score = ||c||^2 - 2 z.c + BIAS strictly positive

typedef __attribute__((ext_vector_type(8))) short short8;   // 8 bf16 in 4 VGPRs
typedef __attribute__((ext_vector_type(4))) float f32x4;

__device__ __forceinline__ unsigned short f2bf(float f) {
  unsigned u = __builtin_bit_cast(unsigned, f);
  unsigned r = u + 0x7FFFu + ((u >> 16) & 1u);   // round-to-nearest-even
  return (unsigned short)(r >> 16);
}

// ---- Kernel 1: out = lat * clamp(lf); zero loss slot ----------------------
__global__ __launch_bounds__(256) void scale_kernel(
    const float* __restrict__ lat, const float* __restrict__ lf_ptr,
    float* __restrict__ out) {
  float lf = lf_ptr[0];
  lf = fminf(fmaxf(lf, 0.001f), 1000.0f);
  int idx = blockIdx.x * blockDim.x + threadIdx.x;
  float4 v = ((const float4*)lat)[idx];
  v.x *= lf; v.y *= lf; v.z *= lf; v.w *= lf;
  ((float4*)out)[idx] = v;
  if (idx == 0) out[TOTAL_ELEMS] = 0.0f;
}

// ---- Kernel 2: centbf[k][d] = bf16(-2*c); cnormb[k] = ||c_k||^2 + BIAS ----
__global__ __launch_bounds__(256) void prep_kernel(
    const float* __restrict__ cent, unsigned short* __restrict__ centbf,
    float* __restrict__ cnormb) {
  int t = blockIdx.x * 256 + threadIdx.x;   // 0..32767
  centbf[t] = f2bf(-2.0f * cent[t]);
  if (t < K) {
    const float* c = cent + t * D;
    float s0 = 0.f, s1 = 0.f, s2 = 0.f, s3 = 0.f;
#pragma unroll
    for (int d = 0; d < D; d += 4) {
      s0 = fmaf(c[d], c[d], s0);
      s1 = fmaf(c[d + 1], c[d + 1], s1);
      s2 = fmaf(c[d + 2], c[d + 2], s2);
      s3 = fmaf(c[d + 3], c[d + 3], s3);
    }
    cnormb[t] = (s0 + s1) + (s2 + s3) + BIAS;
  }
}

// ---- Kernel 3: MFMA argmin + exact fp32 d_min + reduce --------------------
// Wave handles 32 rows (two 16-row A tiles); block = 4 waves = 128 rows.
// score = -2 z.c + (||c||^2 + BIAS) > 0, so fp32 bits compare as uint.
// Pack centroid idx into low 10 mantissa bits -> v_min_u32 = min+argmin.
__global__ __launch_bounds__(256) void vq_kernel(
    const float* __restrict__ lat, const float* __restrict__ cent,
    const unsigned short* __restrict__ centbf, const float* __restrict__ cnormb,
    float* __restrict__ loss_out) {
  const int lane = threadIdx.x & 63;
  const int wave = threadIdx.x >> 6;
  const int quad = lane >> 4;
  const int col  = lane & 15;
  const int rowbase = blockIdx.x * 128 + wave * 32;

  // A-frags: lane holds A[row = col][k = quad*8 + j], j=0..7 (bf16 of z)
  short8 a0, a1;
  {
    const float* p0 = lat + (size_t)(rowbase + col) * D + quad * 8;
    const float* p1 = p0 + 16 * D;
    float4 u0 = ((const float4*)p0)[0], u1 = ((const float4*)p0)[1];
    float4 w0 = ((const float4*)p1)[0], w1 = ((const float4*)p1)[1];
    a0[0] = (short)f2bf(u0.x); a0[1] = (short)f2bf(u0.y);
    a0[2] = (short)f2bf(u0.z); a0[3] = (short)f2bf(u0.w);
    a0[4] = (short)f2bf(u1.x); a0[5] = (short)f2bf(u1.y);
    a0[6] = (short)f2bf(u1.z); a0[7] = (short)f2bf(u1.w);
    a1[0] = (short)f2bf(w0.x); a1[1] = (short)f2bf(w0.y);
    a1[2] = (short)f2bf(w0.z); a1[3] = (short)f2bf(w0.w);
    a1[4] = (short)f2bf(w1.x); a1[5] = (short)f2bf(w1.y);
    a1[6] = (short)f2bf(w1.z); a1[7] = (short)f2bf(w1.w);
  }

  const f32x4 zero = {0.f, 0.f, 0.f, 0.f};
  unsigned pk0[4] = {0xFFFFFFFFu, 0xFFFFFFFFu, 0xFFFFFFFFu, 0xFFFFFFFFu};
  unsigned pk1[4] = {0xFFFFFFFFu, 0xFFFFFFFFu, 0xFFFFFFFFu, 0xFFFFFFFFu};

#pragma unroll 8
  for (int frag = 0; frag < K / 16; ++frag) {
    const int cbase = frag * 16;
    // B-frag: lane holds B[k = quad*8 + j][col] = centbf[cbase+col][quad*8+j]
    short8 b = *(const short8*)(centbf + (size_t)(cbase + col) * D + quad * 8);
    float cn = cnormb[cbase + col];
    f32x4 d0 = __builtin_amdgcn_mfma_f32_16x16x32_bf16(a0, b, zero, 0, 0, 0);
    f32x4 d1 = __builtin_amdgcn_mfma_f32_16x16x32_bf16(a1, b, zero, 0, 0, 0);
    const unsigned idxv = (unsigned)(cbase + col);
#pragma unroll
    for (int r = 0; r < 4; ++r) {
      float s0 = d0[r] + cn;
      unsigned p0 = (__builtin_bit_cast(unsigned, s0) & 0xFFFFFC00u) | idxv;
      pk0[r] = pk0[r] < p0 ? pk0[r] : p0;
      float s1 = d1[r] + cn;
      unsigned p1 = (__builtin_bit_cast(unsigned, s1) & 0xFFFFFC00u) | idxv;
      pk1[r] = pk1[r] < p1 ? pk1[r] : p1;
    }
  }

  // Min across the 16 lanes of each quad-group (cols 0..15 of each row).
#pragma unroll
  for (int off = 1; off < 16; off <<= 1) {
#pragma unroll
    for (int r = 0; r < 4; ++r) {
      unsigned o0 = __shfl_xor(pk0[r], off);
      pk0[r] = pk0[r] < o0 ? pk0[r] : o0;
      unsigned o1 = __shfl_xor(pk1[r], off);
      pk1[r] = pk1[r] < o1 ? pk1[r] : o1;
    }
  }

  // Exact fp32 recompute of d_min for winners.
  // Lane layout: rsel = bits0-1 (which of 4 rows in quad), q = bits2-3 (dim
  // quarter), quad = bits4-5. Row (tile-local) = quad*4 + rsel.
  const int rsel = lane & 3;
  const int q = (lane >> 2) & 3;
  float s = 0.f;
#pragma unroll
  for (int t = 0; t < 2; ++t) {
    unsigned pk = (t == 0) ? pk0[rsel] : pk1[rsel];
    int row = rowbase + t * 16 + quad * 4 + rsel;
    int ci = (int)(pk & 1023u);
    const float* zp = lat + (size_t)row * D + q * 8;
    const float* cp = cent + (size_t)ci * D + q * 8;
    float4 za = ((const float4*)zp)[0], zb = ((const float4*)zp)[1];
    float4 ca = ((const float4*)cp)[0], cb = ((const float4*)cp)[1];
    float f0 = za.x - ca.x, f1 = za.y - ca.y, f2 = za.z - ca.z, f3 = za.w - ca.w;
    float g0 = zb.x - cb.x, g1 = zb.y - cb.y, g2 = zb.z - cb.z, g3 = zb.w - cb.w;
    float m0 = fmaf(f0, f0, g0 * g0);
    float m1 = fmaf(f1, f1, g1 * g1);
    float m2 = fmaf(f2, f2, g2 * g2);
    float m3 = fmaf(f3, f3, g3 * g3);
    s += (m0 + m1) + (m2 + m3);
  }
  // Full 64-lane butterfly sum: every lane's initial s is one dim-quarter of
  // one (row,t) pair -> the all-lane sum counts each of the wave's 32 rows
  // exactly once. (Round-2 bug: an extra *0.25 here undercounted 4x.)
  s += __shfl_xor(s, 4);
  s += __shfl_xor(s, 8);
  s += __shfl_xor(s, 1);
  s += __shfl_xor(s, 2);
  s += __shfl_xor(s, 16);
  s += __shfl_xor(s, 32);

  __shared__ float wsum[4];
  if (lane == 0) wsum[wave] = s;
  __syncthreads();
  if (threadIdx.x == 0) {
    float blk = (wsum[0] + wsum[1]) + (wsum[2] + wsum[3]);
    atomicAdd(loss_out, blk * LOSS_SCALE);
  }
}

extern "C" void kernel_launch(void* const* d_in, const int* in_sizes, int n_in,
                              void* d_out, int out_size, void* d_ws, size_t ws_size,
                              hipStream_t stream) {
  const float* lat  = (const float*)d_in[0];
  const float* cent = (const float*)d_in[1];
  const float* lf   = (const float*)d_in[2];
  float* out = (float*)d_out;
  unsigned short* centbf = (unsigned short*)d_ws;                 // 64 KB
  float* cnormb = (float*)((char*)d_ws + K * D * sizeof(unsigned short));

  scale_kernel<<<TOTAL_ELEMS / 4 / 256, 256, 0, stream>>>(lat, lf, out);
  prep_kernel<<<K * D / 256, 256, 0, stream>>>(cent, centbf, cnormb);
  vq_kernel<<<N_ROWS / 128, 256, 0, stream>>>(lat, cent, centbf, cnormb,
                                              out + TOTAL_ELEMS);
}

// Round 7
// 112.133 us; speedup vs baseline: 3.0579x; 1.0586x over previous
//
#include <hip/hip_runtime.h>

// lat [2048,2048] fp32 -> 131072 rows x D=32; centroids [1024,32] fp32.
// out = [lat * clamp(lf,1e-3,1e3)] ++ [1.25 * mean_{N,D}(min_k ||z-c_k||^2)]
#define D 32
#define K 1024
#define N_ROWS 131072
#define TOTAL_ELEMS 4194304
#define LOSS_SCALE (1.25f / 4194304.0f)
#define BIAS 192.0f   // score = ||c||^2 - 2 z.c + BIAS > 0 -> uint-comparable

typedef __attribute__((ext_vector_type(8))) short short8;   // 8 bf16
typedef __attribute__((ext_vector_type(4))) float f32x4;

__device__ __forceinline__ unsigned short f2bf(float f) {
  unsigned u = __builtin_bit_cast(unsigned, f);
  unsigned r = u + 0x7FFFu + ((u >> 16) & 1u);   // RNE
  return (unsigned short)(r >> 16);
}

// ---- prep: centbf = bf16(-2c); cnormb = ||c||^2 + BIAS; zero loss slot ----
__global__ __launch_bounds__(256) void prep_kernel(
    const float* __restrict__ cent, unsigned short* __restrict__ centbf,
    float* __restrict__ cnormb, float* __restrict__ loss_out) {
  int t = blockIdx.x * 256 + threadIdx.x;   // 0..32767
  centbf[t] = f2bf(-2.0f * cent[t]);
  if (t == 0) *loss_out = 0.0f;
  if (t < K) {
    const float* c = cent + t * D;
    float s0 = 0.f, s1 = 0.f, s2 = 0.f, s3 = 0.f;
#pragma unroll
    for (int d = 0; d < D; d += 4) {
      s0 = fmaf(c[d], c[d], s0);
      s1 = fmaf(c[d + 1], c[d + 1], s1);
      s2 = fmaf(c[d + 2], c[d + 2], s2);
      s3 = fmaf(c[d + 3], c[d + 3], s3);
    }
    cnormb[t] = (s0 + s1) + (s2 + s3) + BIAS;
  }
}

// ---- vq: r3-exact MFMA argmin (2 tiles/wave) + fused scale-store ---------
// Wave = 32 rows (two 16-row A tiles); block = 4 waves = 128 rows; grid 1024.
// f-loop, butterfly, recompute, and block reduction are byte-identical to the
// round-3 PASSING kernel. Only additions: out-store fused into the A-load
// (output-0-verified in r4-r6) and loss zeroed by prep.
__global__ __launch_bounds__(256) void vq_kernel(
    const float* __restrict__ lat, const float* __restrict__ cent,
    const unsigned short* __restrict__ centbf, const float* __restrict__ cnormb,
    const float* __restrict__ lf_ptr, float* __restrict__ out,
    float* __restrict__ loss_out) {
  const int lane = threadIdx.x & 63;
  const int wave = threadIdx.x >> 6;
  const int quad = lane >> 4;
  const int col  = lane & 15;
  const int rowbase = blockIdx.x * 128 + wave * 32;

  // A-frags: lane holds A[row = col][k = quad*8 + j], j=0..7 (bf16 of z)
  // + fused scale-store of out for the same 8 floats.
  float lf = fminf(fmaxf(lf_ptr[0], 0.001f), 1000.0f);
  short8 a0, a1;
  {
    const float* p0 = lat + (size_t)(rowbase + col) * D + quad * 8;
    const float* p1 = p0 + 16 * D;
    float4 u0 = ((const float4*)p0)[0], u1 = ((const float4*)p0)[1];
    float4 w0 = ((const float4*)p1)[0], w1 = ((const float4*)p1)[1];
    a0[0] = (short)f2bf(u0.x); a0[1] = (short)f2bf(u0.y);
    a0[2] = (short)f2bf(u0.z); a0[3] = (short)f2bf(u0.w);
    a0[4] = (short)f2bf(u1.x); a0[5] = (short)f2bf(u1.y);
    a0[6] = (short)f2bf(u1.z); a0[7] = (short)f2bf(u1.w);
    a1[0] = (short)f2bf(w0.x); a1[1] = (short)f2bf(w0.y);
    a1[2] = (short)f2bf(w0.z); a1[3] = (short)f2bf(w0.w);
    a1[4] = (short)f2bf(w1.x); a1[5] = (short)f2bf(w1.y);
    a1[6] = (short)f2bf(w1.z); a1[7] = (short)f2bf(w1.w);
    float* o0 = out + (size_t)(rowbase + col) * D + quad * 8;
    float* o1 = o0 + 16 * D;
    float4 s00 = {u0.x * lf, u0.y * lf, u0.z * lf, u0.w * lf};
    float4 s01 = {u1.x * lf, u1.y * lf, u1.z * lf, u1.w * lf};
    float4 s10 = {w0.x * lf, w0.y * lf, w0.z * lf, w0.w * lf};
    float4 s11 = {w1.x * lf, w1.y * lf, w1.z * lf, w1.w * lf};
    ((float4*)o0)[0] = s00;
    ((float4*)o0)[1] = s01;
    ((float4*)o1)[0] = s10;
    ((float4*)o1)[1] = s11;
  }

  const f32x4 zero = {0.f, 0.f, 0.f, 0.f};
  unsigned pk0[4] = {0xFFFFFFFFu, 0xFFFFFFFFu, 0xFFFFFFFFu, 0xFFFFFFFFu};
  unsigned pk1[4] = {0xFFFFFFFFu, 0xFFFFFFFFu, 0xFFFFFFFFu, 0xFFFFFFFFu};

#pragma unroll 8
  for (int frag = 0; frag < K / 16; ++frag) {
    const int cbase = frag * 16;
    // B-frag: lane holds B[k = quad*8 + j][col] = centbf[cbase+col][quad*8+j]
    short8 b = *(const short8*)(centbf + (size_t)(cbase + col) * D + quad * 8);
    float cn = cnormb[cbase + col];
    f32x4 d0 = __builtin_amdgcn_mfma_f32_16x16x32_bf16(a0, b, zero, 0, 0, 0);
    f32x4 d1 = __builtin_amdgcn_mfma_f32_16x16x32_bf16(a1, b, zero, 0, 0, 0);
    const unsigned idxv = (unsigned)(cbase + col);
#pragma unroll
    for (int r = 0; r < 4; ++r) {
      float s0 = d0[r] + cn;
      unsigned p0 = (__builtin_bit_cast(unsigned, s0) & 0xFFFFFC00u) | idxv;
      pk0[r] = pk0[r] < p0 ? pk0[r] : p0;
      float s1 = d1[r] + cn;
      unsigned p1 = (__builtin_bit_cast(unsigned, s1) & 0xFFFFFC00u) | idxv;
      pk1[r] = pk1[r] < p1 ? pk1[r] : p1;
    }
  }

  // Min across the 16 lanes of each quad-group (cols 0..15 of each row).
#pragma unroll
  for (int off = 1; off < 16; off <<= 1) {
#pragma unroll
    for (int r = 0; r < 4; ++r) {
      unsigned o0 = __shfl_xor(pk0[r], off);
      pk0[r] = pk0[r] < o0 ? pk0[r] : o0;
      unsigned o1 = __shfl_xor(pk1[r], off);
      pk1[r] = pk1[r] < o1 ? pk1[r] : o1;
    }
  }

  // Exact fp32 recompute of d_min for winners (r3-verified lane slicing).
  const int rsel = lane & 3;
  const int q = (lane >> 2) & 3;
  float s = 0.f;
#pragma unroll
  for (int t = 0; t < 2; ++t) {
    unsigned pk = (t == 0) ? pk0[rsel] : pk1[rsel];
    int row = rowbase + t * 16 + quad * 4 + rsel;
    int ci = (int)(pk & 1023u);
    const float* zp = lat + (size_t)row * D + q * 8;
    const float* cp = cent + (size_t)ci * D + q * 8;
    float4 za = ((const float4*)zp)[0], zb = ((const float4*)zp)[1];
    float4 ca = ((const float4*)cp)[0], cb = ((const float4*)cp)[1];
    float f0 = za.x - ca.x, f1 = za.y - ca.y, f2 = za.z - ca.z, f3 = za.w - ca.w;
    float g0 = zb.x - cb.x, g1 = zb.y - cb.y, g2 = zb.z - cb.z, g3 = zb.w - cb.w;
    float m0 = fmaf(f0, f0, g0 * g0);
    float m1 = fmaf(f1, f1, g1 * g1);
    float m2 = fmaf(f2, f2, g2 * g2);
    float m3 = fmaf(f3, f3, g3 * g3);
    s += (m0 + m1) + (m2 + m3);
  }
  // Full 64-lane butterfly: each lane's s is a distinct (row-pair, quarter)
  // slice -> all-lane sum counts each of the wave's 32 rows exactly once.
  s += __shfl_xor(s, 4);
  s += __shfl_xor(s, 8);
  s += __shfl_xor(s, 1);
  s += __shfl_xor(s, 2);
  s += __shfl_xor(s, 16);
  s += __shfl_xor(s, 32);

  __shared__ float wsum[4];
  if (lane == 0) wsum[wave] = s;
  __syncthreads();
  if (threadIdx.x == 0) {
    float blk = (wsum[0] + wsum[1]) + (wsum[2] + wsum[3]);
    atomicAdd(loss_out, blk * LOSS_SCALE);
  }
}

extern "C" void kernel_launch(void* const* d_in, const int* in_sizes, int n_in,
                              void* d_out, int out_size, void* d_ws, size_t ws_size,
                              hipStream_t stream) {
  const float* lat  = (const float*)d_in[0];
  const float* cent = (const float*)d_in[1];
  const float* lf   = (const float*)d_in[2];
  float* out = (float*)d_out;
  unsigned short* centbf = (unsigned short*)d_ws;                 // 64 KB
  float* cnormb = (float*)((char*)d_ws + K * D * sizeof(unsigned short));
  float* loss = out + TOTAL_ELEMS;

  prep_kernel<<<K * D / 256, 256, 0, stream>>>(cent, centbf, cnormb, loss);
  vq_kernel<<<N_ROWS / 128, 256, 0, stream>>>(lat, cent, centbf, cnormb, lf,
                                              out, loss);
}

// Round 8
// 98.139 us; speedup vs baseline: 3.4939x; 1.1426x over previous
//
#include <hip/hip_runtime.h>

// lat [2048,2048] fp32 -> 131072 rows x D=32; centroids [1024,32] fp32.
// out = [lat * clamp(lf,1e-3,1e3)] ++ [1.25 * mean_{N,D}(min_k ||z-c_k||^2)]
#define D 32
#define K 1024
#define N_ROWS 131072
#define TOTAL_ELEMS 4194304
#define LOSS_SCALE (1.25f / 4194304.0f)
#define BIAS 192.0f   // score = ||c||^2 - 2 z.c + BIAS > 0 -> uint-comparable

typedef __attribute__((ext_vector_type(8))) short short8;   // 8 bf16
typedef __attribute__((ext_vector_type(4))) float f32x4;

__device__ __forceinline__ unsigned short f2bf(float f) {
  unsigned u = __builtin_bit_cast(unsigned, f);
  unsigned r = u + 0x7FFFu + ((u >> 16) & 1u);   // RNE
  return (unsigned short)(r >> 16);
}

// ---- prep: centbf = bf16(-2c); cnormb = ||c||^2 + BIAS; zero loss slot ----
__global__ __launch_bounds__(256) void prep_kernel(
    const float* __restrict__ cent, unsigned short* __restrict__ centbf,
    float* __restrict__ cnormb, float* __restrict__ loss_out) {
  int t = blockIdx.x * 256 + threadIdx.x;   // 0..32767
  centbf[t] = f2bf(-2.0f * cent[t]);
  if (t == 0) *loss_out = 0.0f;
  if (t < K) {
    const float* c = cent + t * D;
    float s0 = 0.f, s1 = 0.f, s2 = 0.f, s3 = 0.f;
#pragma unroll
    for (int d = 0; d < D; d += 4) {
      s0 = fmaf(c[d], c[d], s0);
      s1 = fmaf(c[d + 1], c[d + 1], s1);
      s2 = fmaf(c[d + 2], c[d + 2], s2);
      s3 = fmaf(c[d + 3], c[d + 3], s3);
    }
    cnormb[t] = (s0 + s1) + (s2 + s3) + BIAS;
  }
}

// ---- vq: r3-exact 2-tile MFMA argmin + fused scale-store + LDS-B ---------
// Wave = 32 rows; block = 4 waves = 128 rows; grid 1024. Codebook + cnorm
// staged in LDS in two 32KB phases (34 KB/block -> 4 blocks/CU resident).
// f-loop/butterfly/recompute/reduction byte-identical to the r7 PASSING
// kernel; only the B/cn source changed global->LDS (r6 exonerated LDS).
__global__ __launch_bounds__(256) void vq_kernel(
    const float* __restrict__ lat, const float* __restrict__ cent,
    const unsigned short* __restrict__ centbf, const float* __restrict__ cnormb,
    const float* __restrict__ lf_ptr, float* __restrict__ out,
    float* __restrict__ loss_out) {
  __shared__ short8 sB8[2048];   // 32 KB: 512 centroids x 32 bf16 per phase
  __shared__ float sCn[512];     // 2 KB per phase
  __shared__ float wsum[4];
  const int tid = threadIdx.x;
  const int lane = tid & 63;
  const int wave = tid >> 6;
  const int quad = lane >> 4;
  const int col  = lane & 15;
  const int rowbase = blockIdx.x * 128 + wave * 32;

  // A-frags + fused scale-store (r7-verified).
  float lf = fminf(fmaxf(lf_ptr[0], 0.001f), 1000.0f);
  short8 a0, a1;
  {
    const float* p0 = lat + (size_t)(rowbase + col) * D + quad * 8;
    const float* p1 = p0 + 16 * D;
    float4 u0 = ((const float4*)p0)[0], u1 = ((const float4*)p0)[1];
    float4 w0 = ((const float4*)p1)[0], w1 = ((const float4*)p1)[1];
    a0[0] = (short)f2bf(u0.x); a0[1] = (short)f2bf(u0.y);
    a0[2] = (short)f2bf(u0.z); a0[3] = (short)f2bf(u0.w);
    a0[4] = (short)f2bf(u1.x); a0[5] = (short)f2bf(u1.y);
    a0[6] = (short)f2bf(u1.z); a0[7] = (short)f2bf(u1.w);
    a1[0] = (short)f2bf(w0.x); a1[1] = (short)f2bf(w0.y);
    a1[2] = (short)f2bf(w0.z); a1[3] = (short)f2bf(w0.w);
    a1[4] = (short)f2bf(w1.x); a1[5] = (short)f2bf(w1.y);
    a1[6] = (short)f2bf(w1.z); a1[7] = (short)f2bf(w1.w);
    float* o0 = out + (size_t)(rowbase + col) * D + quad * 8;
    float* o1 = o0 + 16 * D;
    float4 s00 = {u0.x * lf, u0.y * lf, u0.z * lf, u0.w * lf};
    float4 s01 = {u1.x * lf, u1.y * lf, u1.z * lf, u1.w * lf};
    float4 s10 = {w0.x * lf, w0.y * lf, w0.z * lf, w0.w * lf};
    float4 s11 = {w1.x * lf, w1.y * lf, w1.z * lf, w1.w * lf};
    ((float4*)o0)[0] = s00;
    ((float4*)o0)[1] = s01;
    ((float4*)o1)[0] = s10;
    ((float4*)o1)[1] = s11;
  }

  const f32x4 zero = {0.f, 0.f, 0.f, 0.f};
  unsigned pk0[4] = {0xFFFFFFFFu, 0xFFFFFFFFu, 0xFFFFFFFFu, 0xFFFFFFFFu};
  unsigned pk1[4] = {0xFFFFFFFFu, 0xFFFFFFFFu, 0xFFFFFFFFu, 0xFFFFFFFFu};

  const short8* gB8 = (const short8*)centbf;   // 4096 short8 total

  for (int p = 0; p < 2; ++p) {
    __syncthreads();   // previous phase's readers done before overwrite
    // Stage 32 KB of codebook + 2 KB of cnorm (coalesced, short8/float).
#pragma unroll
    for (int j = 0; j < 8; ++j)
      sB8[j * 256 + tid] = gB8[p * 2048 + j * 256 + tid];
    sCn[tid] = cnormb[p * 512 + tid];
    sCn[tid + 256] = cnormb[p * 512 + 256 + tid];
    __syncthreads();

#pragma unroll 8
    for (int f = 0; f < 32; ++f) {
      // B-frag: lane holds B[k=quad*8+j][col] of centroid (p*512 + f*16+col);
      // LDS element layout identical to global: row-major 32 bf16/centroid.
      short8 b = sB8[f * 64 + col * 4 + quad];
      float cn = sCn[f * 16 + col];
      f32x4 d0 = __builtin_amdgcn_mfma_f32_16x16x32_bf16(a0, b, zero, 0, 0, 0);
      f32x4 d1 = __builtin_amdgcn_mfma_f32_16x16x32_bf16(a1, b, zero, 0, 0, 0);
      const unsigned idxv = (unsigned)(p * 512 + f * 16 + col);
#pragma unroll
      for (int r = 0; r < 4; ++r) {
        float s0 = d0[r] + cn;
        unsigned q0 = (__builtin_bit_cast(unsigned, s0) & 0xFFFFFC00u) | idxv;
        pk0[r] = pk0[r] < q0 ? pk0[r] : q0;
        float s1 = d1[r] + cn;
        unsigned q1 = (__builtin_bit_cast(unsigned, s1) & 0xFFFFFC00u) | idxv;
        pk1[r] = pk1[r] < q1 ? pk1[r] : q1;
      }
    }
  }

  // Min across the 16 lanes of each quad-group (cols 0..15 of each row).
#pragma unroll
  for (int off = 1; off < 16; off <<= 1) {
#pragma unroll
    for (int r = 0; r < 4; ++r) {
      unsigned o0 = __shfl_xor(pk0[r], off);
      pk0[r] = pk0[r] < o0 ? pk0[r] : o0;
      unsigned o1 = __shfl_xor(pk1[r], off);
      pk1[r] = pk1[r] < o1 ? pk1[r] : o1;
    }
  }

  // Exact fp32 recompute of d_min for winners (r3-verified lane slicing).
  const int rsel = lane & 3;
  const int q = (lane >> 2) & 3;
  float s = 0.f;
#pragma unroll
  for (int t = 0; t < 2; ++t) {
    unsigned pk = (t == 0) ? pk0[rsel] : pk1[rsel];
    int row = rowbase + t * 16 + quad * 4 + rsel;
    int ci = (int)(pk & 1023u);
    const float* zp = lat + (size_t)row * D + q * 8;
    const float* cp = cent + (size_t)ci * D + q * 8;
    float4 za = ((const float4*)zp)[0], zb = ((const float4*)zp)[1];
    float4 ca = ((const float4*)cp)[0], cb = ((const float4*)cp)[1];
    float f0 = za.x - ca.x, f1 = za.y - ca.y, f2 = za.z - ca.z, f3 = za.w - ca.w;
    float g0 = zb.x - cb.x, g1 = zb.y - cb.y, g2 = zb.z - cb.z, g3 = zb.w - cb.w;
    float m0 = fmaf(f0, f0, g0 * g0);
    float m1 = fmaf(f1, f1, g1 * g1);
    float m2 = fmaf(f2, f2, g2 * g2);
    float m3 = fmaf(f3, f3, g3 * g3);
    s += (m0 + m1) + (m2 + m3);
  }
  // Full 64-lane butterfly: each lane's s is a distinct (row-pair, quarter)
  // slice -> all-lane sum counts each of the wave's 32 rows exactly once.
  s += __shfl_xor(s, 4);
  s += __shfl_xor(s, 8);
  s += __shfl_xor(s, 1);
  s += __shfl_xor(s, 2);
  s += __shfl_xor(s, 16);
  s += __shfl_xor(s, 32);

  if (lane == 0) wsum[wave] = s;
  __syncthreads();
  if (threadIdx.x == 0) {
    float blk = (wsum[0] + wsum[1]) + (wsum[2] + wsum[3]);
    atomicAdd(loss_out, blk * LOSS_SCALE);
  }
}

extern "C" void kernel_launch(void* const* d_in, const int* in_sizes, int n_in,
                              void* d_out, int out_size, void* d_ws, size_t ws_size,
                              hipStream_t stream) {
  const float* lat  = (const float*)d_in[0];
  const float* cent = (const float*)d_in[1];
  const float* lf   = (const float*)d_in[2];
  float* out = (float*)d_out;
  unsigned short* centbf = (unsigned short*)d_ws;                 // 64 KB
  float* cnormb = (float*)((char*)d_ws + K * D * sizeof(unsigned short));
  float* loss = out + TOTAL_ELEMS;

  prep_kernel<<<K * D / 256, 256, 0, stream>>>(cent, centbf, cnormb, loss);
  vq_kernel<<<N_ROWS / 128, 256, 0, stream>>>(lat, cent, centbf, cnormb, lf,
                                              out, loss);
}